// Round 1
// baseline (316.035 us; speedup 1.0000x reference)
//
#include <hip/hip_runtime.h>
#include <hip/hip_fp16.h>

#define NSTEPS 30
#define DIM 192
static constexpr long DHW = (long)DIM * DIM * DIM;
static constexpr int PTS_PER_WAVE = 21;   // fallback kernel only

// Shared cofactor 4x4 inverse in double — registers only.
__device__ __forceinline__ void invert4x4_one(const float* __restrict__ aff,
                                              float* __restrict__ out, int b) {
    double a[16];
#pragma unroll
    for (int i = 0; i < 16; i++) a[i] = (double)aff[b * 16 + i];
    double s0 = a[0]*a[5]  - a[4]*a[1];
    double s1 = a[0]*a[6]  - a[4]*a[2];
    double s2 = a[0]*a[7]  - a[4]*a[3];
    double s3 = a[1]*a[6]  - a[5]*a[2];
    double s4 = a[1]*a[7]  - a[5]*a[3];
    double s5 = a[2]*a[7]  - a[6]*a[3];
    double c5 = a[10]*a[15] - a[14]*a[11];
    double c4 = a[9]*a[15]  - a[13]*a[11];
    double c3 = a[9]*a[14]  - a[13]*a[10];
    double c2 = a[8]*a[15]  - a[12]*a[11];
    double c1 = a[8]*a[14]  - a[12]*a[10];
    double c0 = a[8]*a[13]  - a[12]*a[9];
    double det = s0*c5 - s1*c4 + s2*c3 + s3*c2 - s4*c1 + s5*c0;
    double inv = 1.0 / det;
    double o[16];
    o[0]  = ( a[5]*c5 - a[6]*c4 + a[7]*c3) * inv;
    o[1]  = (-a[1]*c5 + a[2]*c4 - a[3]*c3) * inv;
    o[2]  = ( a[13]*s5 - a[14]*s4 + a[15]*s3) * inv;
    o[3]  = (-a[9]*s5 + a[10]*s4 - a[11]*s3) * inv;
    o[4]  = (-a[4]*c5 + a[6]*c2 - a[7]*c1) * inv;
    o[5]  = ( a[0]*c5 - a[2]*c2 + a[3]*c1) * inv;
    o[6]  = (-a[12]*s5 + a[14]*s2 - a[15]*s1) * inv;
    o[7]  = ( a[8]*s5 - a[10]*s2 + a[11]*s1) * inv;
    o[8]  = ( a[4]*c4 - a[5]*c2 + a[7]*c0) * inv;
    o[9]  = (-a[0]*c4 + a[1]*c2 - a[3]*c0) * inv;
    o[10] = ( a[12]*s4 - a[13]*s2 + a[15]*s0) * inv;
    o[11] = (-a[8]*s4 + a[9]*s2 - a[11]*s0) * inv;
    o[12] = (-a[4]*c3 + a[5]*c1 - a[6]*c0) * inv;
    o[13] = ( a[0]*c3 - a[1]*c1 + a[2]*c0) * inv;
    o[14] = (-a[12]*s3 + a[13]*s1 - a[14]*s0) * inv;
    o[15] = ( a[8]*s3 - a[9]*s1 + a[10]*s0) * inv;
#pragma unroll
    for (int i = 0; i < 16; i++) out[b * 16 + i] = (float)o[i];
}

__global__ void invert4x4_kernel(const float* __restrict__ aff,
                                 float* __restrict__ out, int B) {
    int b = blockIdx.x * blockDim.x + threadIdx.x;
    if (b >= B) return;
    invert4x4_one(aff, out, b);
}

// Repack flow (B,3,D,H,W) f32 -> (B,D,H,W,4) fp16, PRE-SCALED by 1/NSTEPS.
// 4 voxels/thread: float4 reads x3, int4 writes x2. Also folds the 4x4
// inverse into the first wave (drops one dispatch).
__global__ __launch_bounds__(256) void repack4_kernel(
    const float* __restrict__ flow, __half* __restrict__ packed,
    const float* __restrict__ aff, float* __restrict__ invaff, int B) {
    if (blockIdx.x == 0 && blockIdx.y == 0 && threadIdx.x < (unsigned)B)
        invert4x4_one(aff, invaff, (int)threadIdx.x);

    long vox = ((long)blockIdx.x * blockDim.x + threadIdx.x) * 4;
    int b = blockIdx.y;
    if (vox >= DHW) return;
    const float* F = flow + (size_t)b * 3 * DHW;
    float4 f0 = *reinterpret_cast<const float4*>(F + vox);
    float4 f1 = *reinterpret_cast<const float4*>(F + vox + DHW);
    float4 f2 = *reinterpret_cast<const float4*>(F + vox + 2 * DHW);
    const float s = (float)(1.0 / NSTEPS);
    union { __half2 h2[4]; int4 i4; } u;
    int4* dst = reinterpret_cast<int4*>(reinterpret_cast<int2*>(packed) +
                                        (size_t)b * DHW + vox);
    u.h2[0] = __floats2half2_rn(f0.x * s, f1.x * s);
    u.h2[1] = __floats2half2_rn(f2.x * s, 0.0f);
    u.h2[2] = __floats2half2_rn(f0.y * s, f1.y * s);
    u.h2[3] = __floats2half2_rn(f2.y * s, 0.0f);
    dst[0] = u.i4;
    u.h2[0] = __floats2half2_rn(f0.z * s, f1.z * s);
    u.h2[1] = __floats2half2_rn(f2.z * s, 0.0f);
    u.h2[2] = __floats2half2_rn(f0.w * s, f1.w * s);
    u.h2[3] = __floats2half2_rn(f2.w * s, 0.0f);
    dst[1] = u.i4;
}

// One lane per point. All 3 channels per 8B gather; no cross-lane traffic.
__global__ __launch_bounds__(256) void deform1_kernel(
    const float* __restrict__ verts,
    const float* __restrict__ affine,
    const __half* __restrict__ packed,     // pre-scaled by 1/NSTEPS
    const float* __restrict__ invaff,
    float* __restrict__ out_pred,
    float* __restrict__ out_flow,
    int N, int B) {
    int pt = blockIdx.x * blockDim.x + threadIdx.x;
    int total = B * N;
    if (pt >= total) return;
    int b = pt / N;
    int n = pt - b * N;

    const float* A = affine + b * 16;
    const float* v = verts + (size_t)pt * 3;
    float vx = v[0], vy = v[1], vz = v[2];
    float x = A[0] * vx + A[1] * vy + A[2]  * vz + A[3];
    float y = A[4] * vx + A[5] * vy + A[6]  * vz + A[7];
    float z = A[8] * vx + A[9] * vy + A[10] * vz + A[11];
    float x0 = x, y0 = y, z0 = z;

    const int2* P = reinterpret_cast<const int2*>(packed) + (size_t)b * DHW;

    // 8 corners x 3 channels, cached per cell. Literal indices only -> regs.
    float cx0, cx1, cx2, cx3, cx4, cx5, cx6, cx7;
    float cy0, cy1, cy2, cy3, cy4, cy5, cy6, cy7;
    float cz0, cz1, cz2, cz3, cz4, cz5, cz6, cz7;
    cx0=cx1=cx2=cx3=cx4=cx5=cx6=cx7=0.f;
    cy0=cy1=cy2=cy3=cy4=cy5=cy6=cy7=0.f;
    cz0=cz1=cz2=cz3=cz4=cz5=cz6=cz7=0.f;
    int key = -1;

    union Cvt { int2 i2; __half2 h2[2]; };

    for (int s = 0; s < NSTEPS; s++) {
        float pd = fminf(fmaxf(x, 0.0f), (float)(DIM - 1));
        float ph = fminf(fmaxf(y, 0.0f), (float)(DIM - 1));
        float pw = fminf(fmaxf(z, 0.0f), (float)(DIM - 1));
        float fd0 = floorf(pd), fh0 = floorf(ph), fw0 = floorf(pw);
        int d0 = (int)fd0, h0 = (int)fh0, w0 = (int)fw0;
        float fd = pd - fd0, fh = ph - fh0, fw = pw - fw0;

        int r00 = (d0 * DIM + h0) * DIM;
        int k = r00 + w0;
        if (k != key) {
            key = k;
            int d1 = min(d0 + 1, DIM - 1);
            int h1 = min(h0 + 1, DIM - 1);
            int w1 = min(w0 + 1, DIM - 1);
            int r01 = (d0 * DIM + h1) * DIM;
            int r10 = (d1 * DIM + h0) * DIM;
            int r11 = (d1 * DIM + h1) * DIM;
            int2 q0 = P[r00 + w0], q1 = P[r00 + w1];
            int2 q2 = P[r01 + w0], q3 = P[r01 + w1];
            int2 q4 = P[r10 + w0], q5 = P[r10 + w1];
            int2 q6 = P[r11 + w0], q7 = P[r11 + w1];
            Cvt u;
            u.i2 = q0; cx0 = __low2float(u.h2[0]); cy0 = __high2float(u.h2[0]); cz0 = __low2float(u.h2[1]);
            u.i2 = q1; cx1 = __low2float(u.h2[0]); cy1 = __high2float(u.h2[0]); cz1 = __low2float(u.h2[1]);
            u.i2 = q2; cx2 = __low2float(u.h2[0]); cy2 = __high2float(u.h2[0]); cz2 = __low2float(u.h2[1]);
            u.i2 = q3; cx3 = __low2float(u.h2[0]); cy3 = __high2float(u.h2[0]); cz3 = __low2float(u.h2[1]);
            u.i2 = q4; cx4 = __low2float(u.h2[0]); cy4 = __high2float(u.h2[0]); cz4 = __low2float(u.h2[1]);
            u.i2 = q5; cx5 = __low2float(u.h2[0]); cy5 = __high2float(u.h2[0]); cz5 = __low2float(u.h2[1]);
            u.i2 = q6; cx6 = __low2float(u.h2[0]); cy6 = __high2float(u.h2[0]); cz6 = __low2float(u.h2[1]);
            u.i2 = q7; cx7 = __low2float(u.h2[0]); cy7 = __high2float(u.h2[0]); cz7 = __low2float(u.h2[1]);
        }

        float wd0 = 1.0f - fd, wh0 = 1.0f - fh, ww0 = 1.0f - fw;
        float a00 = wd0 * wh0, a01 = wd0 * fh, a10 = fd * wh0, a11 = fd * fh;
        float t0 = a00 * ww0, t1 = a00 * fw;
        float t2 = a01 * ww0, t3 = a01 * fw;
        float t4 = a10 * ww0, t5 = a10 * fw;
        float t6 = a11 * ww0, t7 = a11 * fw;
        x += t0*cx0 + t1*cx1 + t2*cx2 + t3*cx3 + t4*cx4 + t5*cx5 + t6*cx6 + t7*cx7;
        y += t0*cy0 + t1*cy1 + t2*cy2 + t3*cy3 + t4*cy4 + t5*cy5 + t6*cy6 + t7*cy7;
        z += t0*cz0 + t1*cz1 + t2*cz2 + t3*cz3 + t4*cz4 + t5*cz5 + t6*cz6 + t7*cz7;
    }

    float fx = x - x0, fy = y - y0, fz = z - z0;
    const float* Ai = invaff + b * 16;
    float ox = Ai[0] * x + Ai[1] * y + Ai[2]  * z + Ai[3];
    float oy = Ai[4] * x + Ai[5] * y + Ai[6]  * z + Ai[7];
    float oz = Ai[8] * x + Ai[9] * y + Ai[10] * z + Ai[11];
    size_t po = (size_t)pt * 3;
    out_pred[po + 0] = ox;
    out_pred[po + 1] = oy;
    out_pred[po + 2] = oz;
    size_t fb = (size_t)b * 3 * N + n;
    out_flow[fb]             = fx;
    out_flow[fb + (size_t)N] = fy;
    out_flow[fb + 2 * (size_t)N] = fz;
}

// Fallback: f32 direct-gather kernel (used only if ws too small).
__global__ __launch_bounds__(256) void deform_kernel(
    const float* __restrict__ verts,
    const float* __restrict__ affine,
    const float* __restrict__ flow,
    const float* __restrict__ invaff,
    float* __restrict__ out_pred,
    float* __restrict__ out_flow,
    int N, int B) {
    int lane = threadIdx.x & 63;
    int wib  = threadIdx.x >> 6;
    long gwave = (long)blockIdx.x * (blockDim.x >> 6) + wib;
    int piw = lane / 3;
    if (piw > PTS_PER_WAVE - 1) piw = PTS_PER_WAVE - 1;
    int ch = lane - piw * 3;
    if (ch > 2) ch = 2;
    long pt = gwave * PTS_PER_WAVE + piw;
    bool valid = (lane < 63) && (pt < (long)B * N);
    long ptc = valid ? pt : ((long)B * N - 1);
    int b = (int)(ptc / N);
    int n = (int)(ptc - (long)b * N);
    const float* A = affine + b * 16;
    const float* v = verts + (size_t)ptc * 3;
    float vx = v[0], vy = v[1], vz = v[2];
    float x = A[0] * vx + A[1] * vy + A[2]  * vz + A[3];
    float y = A[4] * vx + A[5] * vy + A[6]  * vz + A[7];
    float z = A[8] * vx + A[9] * vy + A[10] * vz + A[11];
    float p0 = (ch == 0) ? x : (ch == 1) ? y : z;
    const float* Fc = flow + ((size_t)b * 3 + ch) * (size_t)DHW;
    const float scale = (float)(1.0 / NSTEPS);
    float cc[8];
    int key = -1;
    int bl = piw * 3;
    for (int s = 0; s < NSTEPS; s++) {
        float pd = fminf(fmaxf(x, 0.0f), (float)(DIM - 1));
        float ph = fminf(fmaxf(y, 0.0f), (float)(DIM - 1));
        float pw = fminf(fmaxf(z, 0.0f), (float)(DIM - 1));
        float fd0 = floorf(pd), fh0 = floorf(ph), fw0 = floorf(pw);
        int d0 = (int)fd0, h0 = (int)fh0, w0 = (int)fw0;
        float fd = pd - fd0, fh = ph - fh0, fw = pw - fw0;
        int k = (d0 * DIM + h0) * DIM + w0;
        if (k != key) {
            key = k;
            int d1 = min(d0 + 1, DIM - 1);
            int h1 = min(h0 + 1, DIM - 1);
            int w1 = min(w0 + 1, DIM - 1);
            int r00 = (d0 * DIM + h0) * DIM;
            int r01 = (d0 * DIM + h1) * DIM;
            int r10 = (d1 * DIM + h0) * DIM;
            int r11 = (d1 * DIM + h1) * DIM;
            cc[0] = Fc[r00 + w0] * scale;
            cc[1] = Fc[r00 + w1] * scale;
            cc[2] = Fc[r01 + w0] * scale;
            cc[3] = Fc[r01 + w1] * scale;
            cc[4] = Fc[r10 + w0] * scale;
            cc[5] = Fc[r10 + w1] * scale;
            cc[6] = Fc[r11 + w0] * scale;
            cc[7] = Fc[r11 + w1] * scale;
        }
        float omfw = 1.0f - fw, omfh = 1.0f - fh, omfd = 1.0f - fd;
        float c00 = cc[0] * omfw + cc[1] * fw;
        float c01 = cc[2] * omfw + cc[3] * fw;
        float c10 = cc[4] * omfw + cc[5] * fw;
        float c11 = cc[6] * omfw + cc[7] * fw;
        float c0 = c00 * omfh + c01 * fh;
        float c1 = c10 * omfh + c11 * fh;
        float val = c0 * omfd + c1 * fd;
        float v0 = __shfl(val, bl,     64);
        float v1 = __shfl(val, bl + 1, 64);
        float v2 = __shfl(val, bl + 2, 64);
        x += v0; y += v1; z += v2;
    }
    if (valid) {
        float posc = (ch == 0) ? x : (ch == 1) ? y : z;
        float fint = posc - p0;
        const float* Ai = invaff + b * 16 + ch * 4;
        float o = Ai[0] * x + Ai[1] * y + Ai[2] * z + Ai[3];
        out_pred[(size_t)ptc * 3 + ch] = o;
        out_flow[(size_t)b * 3 * N + (size_t)ch * N + n] = fint;
    }
}

extern "C" void kernel_launch(void* const* d_in, const int* in_sizes, int n_in,
                              void* d_out, int out_size, void* d_ws, size_t ws_size,
                              hipStream_t stream) {
    const float* verts  = (const float*)d_in[0];
    const float* affine = (const float*)d_in[1];
    const float* flow   = (const float*)d_in[2];

    int B = in_sizes[1] / 16;          // affine is B*4*4
    int N = in_sizes[0] / (3 * B);     // verts is B*N*3

    float* out_pred = (float*)d_out;                      // (B,N,3)
    float* out_flow = out_pred + (size_t)B * N * 3;       // (B,3,N)

    size_t packed_bytes = (size_t)B * DHW * 4 * sizeof(__half);  // 8B/voxel
    bool use_packed = (ws_size >= packed_bytes + 256);

    if (use_packed) {
        __half* packed = (__half*)d_ws;
        float* invaff  = (float*)((char*)d_ws + packed_bytes);
        long vblocks = (DHW / 4 + 255) / 256;
        hipLaunchKernelGGL(repack4_kernel, dim3((unsigned)vblocks, B), dim3(256),
                           0, stream, flow, packed, affine, invaff, B);
        int total = B * N;
        int blocks = (total + 255) / 256;
        hipLaunchKernelGGL(deform1_kernel, dim3((unsigned)blocks), dim3(256),
                           0, stream, verts, affine, packed, invaff,
                           out_pred, out_flow, N, B);
    } else {
        float* invaff = (float*)d_ws;
        long total_pts = (long)B * N;
        long waves  = (total_pts + PTS_PER_WAVE - 1) / PTS_PER_WAVE;
        long blocks = (waves + 3) / 4;
        hipLaunchKernelGGL(invert4x4_kernel, dim3(1), dim3(64), 0, stream,
                           affine, invaff, B);
        hipLaunchKernelGGL(deform_kernel, dim3((unsigned)blocks), dim3(256), 0,
                           stream, verts, affine, flow, invaff,
                           out_pred, out_flow, N, B);
    }
}

// Round 2
// 314.361 us; speedup vs baseline: 1.0053x; 1.0053x over previous
//
#include <hip/hip_runtime.h>
#include <hip/hip_fp16.h>

#define NSTEPS 30
#define DIM 192
static constexpr long DHW = (long)DIM * DIM * DIM;
static constexpr int PTS_PER_WAVE = 21;   // 3 lanes per point, lane 63 idle

// Shared cofactor 4x4 inverse in double — registers only.
__device__ __forceinline__ void invert4x4_one(const float* __restrict__ aff,
                                              float* __restrict__ out, int b) {
    double a[16];
#pragma unroll
    for (int i = 0; i < 16; i++) a[i] = (double)aff[b * 16 + i];
    double s0 = a[0]*a[5]  - a[4]*a[1];
    double s1 = a[0]*a[6]  - a[4]*a[2];
    double s2 = a[0]*a[7]  - a[4]*a[3];
    double s3 = a[1]*a[6]  - a[5]*a[2];
    double s4 = a[1]*a[7]  - a[5]*a[3];
    double s5 = a[2]*a[7]  - a[6]*a[3];
    double c5 = a[10]*a[15] - a[14]*a[11];
    double c4 = a[9]*a[15]  - a[13]*a[11];
    double c3 = a[9]*a[14]  - a[13]*a[10];
    double c2 = a[8]*a[15]  - a[12]*a[11];
    double c1 = a[8]*a[14]  - a[12]*a[10];
    double c0 = a[8]*a[13]  - a[12]*a[9];
    double det = s0*c5 - s1*c4 + s2*c3 + s3*c2 - s4*c1 + s5*c0;
    double inv = 1.0 / det;
    double o[16];
    o[0]  = ( a[5]*c5 - a[6]*c4 + a[7]*c3) * inv;
    o[1]  = (-a[1]*c5 + a[2]*c4 - a[3]*c3) * inv;
    o[2]  = ( a[13]*s5 - a[14]*s4 + a[15]*s3) * inv;
    o[3]  = (-a[9]*s5 + a[10]*s4 - a[11]*s3) * inv;
    o[4]  = (-a[4]*c5 + a[6]*c2 - a[7]*c1) * inv;
    o[5]  = ( a[0]*c5 - a[2]*c2 + a[3]*c1) * inv;
    o[6]  = (-a[12]*s5 + a[14]*s2 - a[15]*s1) * inv;
    o[7]  = ( a[8]*s5 - a[10]*s2 + a[11]*s1) * inv;
    o[8]  = ( a[4]*c4 - a[5]*c2 + a[7]*c0) * inv;
    o[9]  = (-a[0]*c4 + a[1]*c2 - a[3]*c0) * inv;
    o[10] = ( a[12]*s4 - a[13]*s2 + a[15]*s0) * inv;
    o[11] = (-a[8]*s4 + a[9]*s2 - a[11]*s0) * inv;
    o[12] = (-a[4]*c3 + a[5]*c1 - a[6]*c0) * inv;
    o[13] = ( a[0]*c3 - a[1]*c1 + a[2]*c0) * inv;
    o[14] = (-a[12]*s3 + a[13]*s1 - a[14]*s0) * inv;
    o[15] = ( a[8]*s3 - a[9]*s1 + a[10]*s0) * inv;
#pragma unroll
    for (int i = 0; i < 16; i++) out[b * 16 + i] = (float)o[i];
}

__global__ void invert4x4_kernel(const float* __restrict__ aff,
                                 float* __restrict__ out, int B) {
    int b = blockIdx.x * blockDim.x + threadIdx.x;
    if (b >= B) return;
    invert4x4_one(aff, out, b);
}

// Repack flow (B,3,D,H,W) f32 -> (B,D,H,W,4) fp16, NOT pre-scaled (the
// 3-lane deform kernel applies 1/NSTEPS itself, matching the proven r0
// numerics). 4 voxels/thread: float4 reads x3, int4 writes x2. Folds the
// 4x4 inverse into the first wave (drops one dispatch).
__global__ __launch_bounds__(256) void repack4_kernel(
    const float* __restrict__ flow, __half* __restrict__ packed,
    const float* __restrict__ aff, float* __restrict__ invaff, int B) {
    if (blockIdx.x == 0 && blockIdx.y == 0 && threadIdx.x < (unsigned)B)
        invert4x4_one(aff, invaff, (int)threadIdx.x);

    long vox = ((long)blockIdx.x * blockDim.x + threadIdx.x) * 4;
    int b = blockIdx.y;
    if (vox >= DHW) return;
    const float* F = flow + (size_t)b * 3 * DHW;
    float4 f0 = *reinterpret_cast<const float4*>(F + vox);
    float4 f1 = *reinterpret_cast<const float4*>(F + vox + DHW);
    float4 f2 = *reinterpret_cast<const float4*>(F + vox + 2 * DHW);
    union { __half2 h2[4]; int4 i4; } u;
    int4* dst = reinterpret_cast<int4*>(reinterpret_cast<int2*>(packed) +
                                        (size_t)b * DHW + vox);
    u.h2[0] = __floats2half2_rn(f0.x, f1.x);
    u.h2[1] = __floats2half2_rn(f2.x, 0.0f);
    u.h2[2] = __floats2half2_rn(f0.y, f1.y);
    u.h2[3] = __floats2half2_rn(f2.y, 0.0f);
    dst[0] = u.i4;
    u.h2[0] = __floats2half2_rn(f0.z, f1.z);
    u.h2[1] = __floats2half2_rn(f2.z, 0.0f);
    u.h2[2] = __floats2half2_rn(f0.w, f1.w);
    u.h2[3] = __floats2half2_rn(f2.w, 0.0f);
    dst[1] = u.i4;
}

// 3 lanes per point, gathering from the interleaved fp16 volume.
// 280k pts / 21 per wave = 13334 waves -> 8 waves/SIMD residency, which is
// what hides the per-step divergent-gather latency (r1's 1-lane variant at
// 4.3 waves/SIMD regressed +16us).
__global__ __launch_bounds__(256) void deform_packed_kernel(
    const float* __restrict__ verts,
    const float* __restrict__ affine,
    const __half* __restrict__ packed,
    const float* __restrict__ invaff,
    float* __restrict__ out_pred,
    float* __restrict__ out_flow,
    int N, int B) {
    int lane = threadIdx.x & 63;
    int wib  = threadIdx.x >> 6;
    long gwave = (long)blockIdx.x * (blockDim.x >> 6) + wib;

    int piw = lane / 3;
    if (piw > PTS_PER_WAVE - 1) piw = PTS_PER_WAVE - 1;
    int ch = lane - piw * 3;
    if (ch > 2) ch = 2;

    long pt = gwave * PTS_PER_WAVE + piw;
    bool valid = (lane < 63) && (pt < (long)B * N);
    long ptc = valid ? pt : ((long)B * N - 1);
    int b = (int)(ptc / N);
    int n = (int)(ptc - (long)b * N);

    const float* A = affine + b * 16;
    const float* v = verts + (size_t)ptc * 3;
    float vx = v[0], vy = v[1], vz = v[2];
    float x = A[0] * vx + A[1] * vy + A[2]  * vz + A[3];
    float y = A[4] * vx + A[5] * vy + A[6]  * vz + A[7];
    float z = A[8] * vx + A[9] * vy + A[10] * vz + A[11];
    float p0 = (ch == 0) ? x : (ch == 1) ? y : z;

    // own-channel base into the interleaved volume (units: halves)
    const __half* Pb = packed + ((size_t)b * DHW) * 4 + ch;
    const float scale = (float)(1.0 / NSTEPS);

    float cc[8];
    int key = -1;
    int bl = piw * 3;

    for (int s = 0; s < NSTEPS; s++) {
        float pd = fminf(fmaxf(x, 0.0f), (float)(DIM - 1));
        float ph = fminf(fmaxf(y, 0.0f), (float)(DIM - 1));
        float pw = fminf(fmaxf(z, 0.0f), (float)(DIM - 1));
        float fd0 = floorf(pd), fh0 = floorf(ph), fw0 = floorf(pw);
        int d0 = (int)fd0, h0 = (int)fh0, w0 = (int)fw0;
        float fd = pd - fd0, fh = ph - fh0, fw = pw - fw0;

        int k = (d0 * DIM + h0) * DIM + w0;
        if (k != key) {
            key = k;
            int d1 = min(d0 + 1, DIM - 1);
            int h1 = min(h0 + 1, DIM - 1);
            int w1 = min(w0 + 1, DIM - 1);
            size_t r00 = (size_t)((d0 * DIM + h0) * DIM) * 4;
            size_t r01 = (size_t)((d0 * DIM + h1) * DIM) * 4;
            size_t r10 = (size_t)((d1 * DIM + h0) * DIM) * 4;
            size_t r11 = (size_t)((d1 * DIM + h1) * DIM) * 4;
            size_t o0 = (size_t)w0 * 4, o1 = (size_t)w1 * 4;
            cc[0] = __half2float(Pb[r00 + o0]) * scale;
            cc[1] = __half2float(Pb[r00 + o1]) * scale;
            cc[2] = __half2float(Pb[r01 + o0]) * scale;
            cc[3] = __half2float(Pb[r01 + o1]) * scale;
            cc[4] = __half2float(Pb[r10 + o0]) * scale;
            cc[5] = __half2float(Pb[r10 + o1]) * scale;
            cc[6] = __half2float(Pb[r11 + o0]) * scale;
            cc[7] = __half2float(Pb[r11 + o1]) * scale;
        }

        float omfw = 1.0f - fw, omfh = 1.0f - fh, omfd = 1.0f - fd;
        float c00 = cc[0] * omfw + cc[1] * fw;
        float c01 = cc[2] * omfw + cc[3] * fw;
        float c10 = cc[4] * omfw + cc[5] * fw;
        float c11 = cc[6] * omfw + cc[7] * fw;
        float c0 = c00 * omfh + c01 * fh;
        float c1 = c10 * omfh + c11 * fh;
        float val = c0 * omfd + c1 * fd;

        float v0 = __shfl(val, bl,     64);
        float v1 = __shfl(val, bl + 1, 64);
        float v2 = __shfl(val, bl + 2, 64);
        x += v0; y += v1; z += v2;
    }

    if (valid) {
        float posc = (ch == 0) ? x : (ch == 1) ? y : z;
        float fint = posc - p0;
        const float* Ai = invaff + b * 16 + ch * 4;
        float o = Ai[0] * x + Ai[1] * y + Ai[2] * z + Ai[3];
        out_pred[(size_t)ptc * 3 + ch] = o;
        out_flow[(size_t)b * 3 * N + (size_t)ch * N + n] = fint;
    }
}

// Fallback: f32 direct-gather kernel (used only if ws too small).
__global__ __launch_bounds__(256) void deform_kernel(
    const float* __restrict__ verts,
    const float* __restrict__ affine,
    const float* __restrict__ flow,
    const float* __restrict__ invaff,
    float* __restrict__ out_pred,
    float* __restrict__ out_flow,
    int N, int B) {
    int lane = threadIdx.x & 63;
    int wib  = threadIdx.x >> 6;
    long gwave = (long)blockIdx.x * (blockDim.x >> 6) + wib;
    int piw = lane / 3;
    if (piw > PTS_PER_WAVE - 1) piw = PTS_PER_WAVE - 1;
    int ch = lane - piw * 3;
    if (ch > 2) ch = 2;
    long pt = gwave * PTS_PER_WAVE + piw;
    bool valid = (lane < 63) && (pt < (long)B * N);
    long ptc = valid ? pt : ((long)B * N - 1);
    int b = (int)(ptc / N);
    int n = (int)(ptc - (long)b * N);
    const float* A = affine + b * 16;
    const float* v = verts + (size_t)ptc * 3;
    float vx = v[0], vy = v[1], vz = v[2];
    float x = A[0] * vx + A[1] * vy + A[2]  * vz + A[3];
    float y = A[4] * vx + A[5] * vy + A[6]  * vz + A[7];
    float z = A[8] * vx + A[9] * vy + A[10] * vz + A[11];
    float p0 = (ch == 0) ? x : (ch == 1) ? y : z;
    const float* Fc = flow + ((size_t)b * 3 + ch) * (size_t)DHW;
    const float scale = (float)(1.0 / NSTEPS);
    float cc[8];
    int key = -1;
    int bl = piw * 3;
    for (int s = 0; s < NSTEPS; s++) {
        float pd = fminf(fmaxf(x, 0.0f), (float)(DIM - 1));
        float ph = fminf(fmaxf(y, 0.0f), (float)(DIM - 1));
        float pw = fminf(fmaxf(z, 0.0f), (float)(DIM - 1));
        float fd0 = floorf(pd), fh0 = floorf(ph), fw0 = floorf(pw);
        int d0 = (int)fd0, h0 = (int)fh0, w0 = (int)fw0;
        float fd = pd - fd0, fh = ph - fh0, fw = pw - fw0;
        int k = (d0 * DIM + h0) * DIM + w0;
        if (k != key) {
            key = k;
            int d1 = min(d0 + 1, DIM - 1);
            int h1 = min(h0 + 1, DIM - 1);
            int w1 = min(w0 + 1, DIM - 1);
            int r00 = (d0 * DIM + h0) * DIM;
            int r01 = (d0 * DIM + h1) * DIM;
            int r10 = (d1 * DIM + h0) * DIM;
            int r11 = (d1 * DIM + h1) * DIM;
            cc[0] = Fc[r00 + w0] * scale;
            cc[1] = Fc[r00 + w1] * scale;
            cc[2] = Fc[r01 + w0] * scale;
            cc[3] = Fc[r01 + w1] * scale;
            cc[4] = Fc[r10 + w0] * scale;
            cc[5] = Fc[r10 + w1] * scale;
            cc[6] = Fc[r11 + w0] * scale;
            cc[7] = Fc[r11 + w1] * scale;
        }
        float omfw = 1.0f - fw, omfh = 1.0f - fh, omfd = 1.0f - fd;
        float c00 = cc[0] * omfw + cc[1] * fw;
        float c01 = cc[2] * omfw + cc[3] * fw;
        float c10 = cc[4] * omfw + cc[5] * fw;
        float c11 = cc[6] * omfw + cc[7] * fw;
        float c0 = c00 * omfh + c01 * fh;
        float c1 = c10 * omfh + c11 * fh;
        float val = c0 * omfd + c1 * fd;
        float v0 = __shfl(val, bl,     64);
        float v1 = __shfl(val, bl + 1, 64);
        float v2 = __shfl(val, bl + 2, 64);
        x += v0; y += v1; z += v2;
    }
    if (valid) {
        float posc = (ch == 0) ? x : (ch == 1) ? y : z;
        float fint = posc - p0;
        const float* Ai = invaff + b * 16 + ch * 4;
        float o = Ai[0] * x + Ai[1] * y + Ai[2] * z + Ai[3];
        out_pred[(size_t)ptc * 3 + ch] = o;
        out_flow[(size_t)b * 3 * N + (size_t)ch * N + n] = fint;
    }
}

extern "C" void kernel_launch(void* const* d_in, const int* in_sizes, int n_in,
                              void* d_out, int out_size, void* d_ws, size_t ws_size,
                              hipStream_t stream) {
    const float* verts  = (const float*)d_in[0];
    const float* affine = (const float*)d_in[1];
    const float* flow   = (const float*)d_in[2];

    int B = in_sizes[1] / 16;          // affine is B*4*4
    int N = in_sizes[0] / (3 * B);     // verts is B*N*3

    float* out_pred = (float*)d_out;                      // (B,N,3)
    float* out_flow = out_pred + (size_t)B * N * 3;       // (B,3,N)

    size_t packed_bytes = (size_t)B * DHW * 4 * sizeof(__half);  // 8B/voxel
    bool use_packed = (ws_size >= packed_bytes + 256);

    long total_pts = (long)B * N;
    long waves  = (total_pts + PTS_PER_WAVE - 1) / PTS_PER_WAVE;
    long blocks = (waves + 3) / 4;     // 4 waves per 256-thread block

    if (use_packed) {
        __half* packed = (__half*)d_ws;
        float* invaff  = (float*)((char*)d_ws + packed_bytes);
        long vblocks = (DHW / 4 + 255) / 256;
        hipLaunchKernelGGL(repack4_kernel, dim3((unsigned)vblocks, B), dim3(256),
                           0, stream, flow, packed, affine, invaff, B);
        hipLaunchKernelGGL(deform_packed_kernel, dim3((unsigned)blocks), dim3(256),
                           0, stream, verts, affine, packed, invaff,
                           out_pred, out_flow, N, B);
    } else {
        float* invaff = (float*)d_ws;
        hipLaunchKernelGGL(invert4x4_kernel, dim3(1), dim3(64), 0, stream,
                           affine, invaff, B);
        hipLaunchKernelGGL(deform_kernel, dim3((unsigned)blocks), dim3(256), 0,
                           stream, verts, affine, flow, invaff,
                           out_pred, out_flow, N, B);
    }
}